// Round 13
// baseline (151.696 us; speedup 1.0000x reference)
//
#include <hip/hip_runtime.h>

// Problem constants: b=32, d=256, h=32, w=128
#define BB 32
#define DD 256
#define HW 4096
#define DHW (DD * HW)        // 2^20
#define EPS 1e-5f

#define SIB 4                // sibling blocks per channel
#define BPB (BB / SIB)       // 8 batches per block
#define NBLK (DD * SIB)      // 1024 blocks x 256 threads; 4 blocks/CU (capacity 8)

// ws layout: floats [0,4096): per-block partials (bid*4 + {sum,sq,cnt,pad})
//            bytes [16384,17408): 256 per-channel arrival counters (uint)
#define WS_CTR_BYTE 16384

typedef float floatx4 __attribute__((ext_vector_type(4)));

__global__ void __launch_bounds__(256, 8)
channel_kernel(const float* __restrict__ x, const int* __restrict__ mask,
               const float* __restrict__ gamma, const float* __restrict__ beta,
               float* __restrict__ ws, float* __restrict__ out) {
    const int bid = blockIdx.x;
    const int d = bid >> 2;              // channel
    const int g = bid & 3;               // sibling index
    const int b0 = g * BPB;
    const int tid = threadIdx.x;         // 0..255
    const int wave = tid >> 6, lane = tid & 63;

    const float4* __restrict__ xv4 = reinterpret_cast<const float4*>(x);
    const int4*   __restrict__ mv4 = reinterpret_cast<const int4*>(mask);
    const int sbase = d * 1024 + tid;    // float4 base within a (b, d) slice

    // ---- Phase A: 8 batches, 4+4 staged loads per batch ----
    float sum = 0.f, sq = 0.f, cnt = 0.f;
#pragma unroll 1
    for (int bb = 0; bb < BPB; ++bb) {
        const int b = b0 + bb;
        float4 xs[4];
        int4   ms[4];
#pragma unroll
        for (int j = 0; j < 4; ++j) {
            xs[j] = xv4[b * (DHW / 4) + sbase + j * 256];
            ms[j] = mv4[b * 1024 + j * 256 + tid];
        }
#pragma unroll
        for (int j = 0; j < 4; ++j) {
            const float vx = ms[j].x ? 0.f : xs[j].x;
            const float vy = ms[j].y ? 0.f : xs[j].y;
            const float vz = ms[j].z ? 0.f : xs[j].z;
            const float vw = ms[j].w ? 0.f : xs[j].w;
            sum += vx + vy + vz + vw;
            sq  += vx * vx + vy * vy + vz * vz + vw * vw;
            cnt += (ms[j].x ? 0.f : 1.f) + (ms[j].y ? 0.f : 1.f)
                 + (ms[j].z ? 0.f : 1.f) + (ms[j].w ? 0.f : 1.f);
        }
    }

    // ---- Block reduce 256 -> 1 ----
    __shared__ float rsum[4], rsq[4], rcnt[4];
    __shared__ float s_scale, s_bias;
#pragma unroll
    for (int off = 32; off > 0; off >>= 1) {
        sum += __shfl_down(sum, off);
        sq  += __shfl_down(sq, off);
        cnt += __shfl_down(cnt, off);
    }
    if (lane == 0) { rsum[wave] = sum; rsq[wave] = sq; rcnt[wave] = cnt; }
    __syncthreads();

    unsigned* ctr = reinterpret_cast<unsigned*>(
        reinterpret_cast<char*>(ws) + WS_CTR_BYTE) + d;
    if (tid == 0) {
        float ts = rsum[0] + rsum[1] + rsum[2] + rsum[3];
        float tq = rsq[0] + rsq[1] + rsq[2] + rsq[3];
        float tc = rcnt[0] + rcnt[1] + rcnt[2] + rcnt[3];
        ws[bid * 4 + 0] = ts;            // disjoint slots, plain stores
        ws[bid * 4 + 1] = tq;
        ws[bid * 4 + 2] = tc;
        __threadfence();                 // make partials visible device-wide
        __hip_atomic_fetch_add(ctr, 1u, __ATOMIC_RELEASE, __HIP_MEMORY_SCOPE_AGENT);
        // ---- per-channel sync: wait for the 3 siblings only ----
        while (__hip_atomic_load(ctr, __ATOMIC_ACQUIRE, __HIP_MEMORY_SCOPE_AGENT)
               < (unsigned)SIB) {
            __builtin_amdgcn_s_sleep(1);
        }
        // deterministic fixed-order merge of the 4 sibling partials
        float fs = 0.f, fq = 0.f, fc = 0.f;
#pragma unroll
        for (int s = 0; s < SIB; ++s) {
            const int sb = (d * SIB + s) * 4;
            fs += __hip_atomic_load(&ws[sb + 0], __ATOMIC_RELAXED, __HIP_MEMORY_SCOPE_AGENT);
            fq += __hip_atomic_load(&ws[sb + 1], __ATOMIC_RELAXED, __HIP_MEMORY_SCOPE_AGENT);
            fc += __hip_atomic_load(&ws[sb + 2], __ATOMIC_RELAXED, __HIP_MEMORY_SCOPE_AGENT);
        }
        fc = fmaxf(fc, 1.0f);
        const float mean = fs / fc;
        const float var = fmaxf(fq / fc - mean * mean, 0.0f);
        const float sc = rsqrtf(var + EPS) * gamma[d];
        s_scale = sc;
        s_bias = beta[d] - mean * sc;
    }
    __syncthreads();
    const float sc = s_scale, bi = s_bias;

    // ---- Phase C: re-read own 8 slices (L2/L3-warm) + nt-store out ----
    floatx4* __restrict__ ov4 = reinterpret_cast<floatx4*>(out);
#pragma unroll 1
    for (int bb = 0; bb < BPB; ++bb) {
        const int b = b0 + bb;
        float4 xs[4];
        int4   ms[4];
#pragma unroll
        for (int j = 0; j < 4; ++j) {
            xs[j] = xv4[b * (DHW / 4) + sbase + j * 256];
            ms[j] = mv4[b * 1024 + j * 256 + tid];
        }
#pragma unroll
        for (int j = 0; j < 4; ++j) {
            floatx4 o;
            o.x = ms[j].x ? xs[j].x : xs[j].x * sc + bi;
            o.y = ms[j].y ? xs[j].y : xs[j].y * sc + bi;
            o.z = ms[j].z ? xs[j].z : xs[j].z * sc + bi;
            o.w = ms[j].w ? xs[j].w : xs[j].w * sc + bi;
            __builtin_nontemporal_store(o, &ov4[b * (DHW / 4) + sbase + j * 256]);
        }
    }
}

extern "C" void kernel_launch(void* const* d_in, const int* in_sizes, int n_in,
                              void* d_out, int out_size, void* d_ws, size_t ws_size,
                              hipStream_t stream) {
    const float* x     = (const float*)d_in[0];
    const int*   mask  = (const int*)d_in[1];
    const float* gamma = (const float*)d_in[2];
    const float* beta  = (const float*)d_in[3];
    float* out = (float*)d_out;
    float* ws  = (float*)d_ws;

    // Zero the 256 per-channel counters (1 KB); ws is not re-poisoned between
    // replays, and the graph replays this memset each call.
    hipMemsetAsync((char*)d_ws + WS_CTR_BYTE, 0, DD * sizeof(unsigned), stream);
    channel_kernel<<<NBLK, 256, 0, stream>>>(x, mask, gamma, beta, ws, out);
}

// Round 14
// 84.622 us; speedup vs baseline: 1.7926x; 1.7926x over previous
//
#include <hip/hip_runtime.h>

// Problem constants: b=32, d=256, h=32, w=128
#define BB 32
#define DD 256
#define HW 4096
#define DHW (DD * HW)        // 2^20
#define EPS 1e-5f

typedef float floatx4 __attribute__((ext_vector_type(4)));

// Twin blocks per channel: bid = 2*d + half. BOTH twins run the full phase A
// over all 32 batches (identical data, identical order -> bit-identical
// scale/bias; the second reader's loads hit L3 since x (128 MiB) fits in the
// 256 MiB Infinity Cache and phase A is read-only). Phase C is split by twin:
// half 0 writes b=0..15, half 1 writes b=16..31. No cross-block sync at all.
// 512 blocks x 1024 threads, VGPR<=64 -> 2 blocks/CU = 32 waves/CU.
__global__ void __launch_bounds__(1024, 8)
channel_kernel(const float* __restrict__ x, const int* __restrict__ mask,
               const float* __restrict__ gamma, const float* __restrict__ beta,
               float* __restrict__ out) {
    const int d = blockIdx.x >> 1;       // channel
    const int half = blockIdx.x & 1;     // which 16 batches this twin writes
    const int tid = threadIdx.x;         // 0..1023
    const int wave = tid >> 6, lane = tid & 63;

    const float4* __restrict__ xv4 = reinterpret_cast<const float4*>(x);
    const int4*   __restrict__ mv4 = reinterpret_cast<const int4*>(mask);
    const int xbase = d * 1024 + tid;    // float4 index of (b=0, d, 4*tid)

    // ---- Phase A: full masked accumulation over ALL 32 batches ----
    float sum = 0.f, sq = 0.f, cnt = 0.f;
#pragma unroll 8
    for (int b = 0; b < BB; ++b) {
        float4 xv = xv4[b * (DHW / 4) + xbase];
        int4  mv = mv4[b * 1024 + tid];
        if (!mv.x) { sum += xv.x; sq += xv.x * xv.x; cnt += 1.f; }
        if (!mv.y) { sum += xv.y; sq += xv.y * xv.y; cnt += 1.f; }
        if (!mv.z) { sum += xv.z; sq += xv.z * xv.z; cnt += 1.f; }
        if (!mv.w) { sum += xv.w; sq += xv.w * xv.w; cnt += 1.f; }
    }

    // ---- Phase B: block reduce (1024 -> 1), compute scale/bias ----
    __shared__ float rsum[16], rsq[16], rcnt[16];
    __shared__ float s_scale, s_bias;
#pragma unroll
    for (int off = 32; off > 0; off >>= 1) {
        sum += __shfl_down(sum, off);
        sq  += __shfl_down(sq, off);
        cnt += __shfl_down(cnt, off);
    }
    if (lane == 0) { rsum[wave] = sum; rsq[wave] = sq; rcnt[wave] = cnt; }
    __syncthreads();
    if (tid < 16) {
        float ts = rsum[tid], tq = rsq[tid], tc = rcnt[tid];
#pragma unroll
        for (int off = 8; off > 0; off >>= 1) {
            ts += __shfl_down(ts, off, 16);
            tq += __shfl_down(tq, off, 16);
            tc += __shfl_down(tc, off, 16);
        }
        if (tid == 0) {
            tc = fmaxf(tc, 1.0f);
            const float mean = ts / tc;
            const float var = fmaxf(tq / tc - mean * mean, 0.0f);
            const float sc = rsqrtf(var + EPS) * gamma[d];
            s_scale = sc;
            s_bias = beta[d] - mean * sc;
        }
    }
    __syncthreads();
    const float sc = s_scale, bi = s_bias;

    // ---- Phase C: this twin's 16 batches (x re-read = L3 hit) + nt-store ----
    floatx4* __restrict__ ov4 = reinterpret_cast<floatx4*>(out);
    const int blo = half * 16, bhi = blo + 16;
#pragma unroll 8
    for (int b = blo; b < bhi; ++b) {
        float4 xv = xv4[b * (DHW / 4) + xbase];
        int4  mv = mv4[b * 1024 + tid];
        floatx4 o;
        o.x = mv.x ? xv.x : xv.x * sc + bi;
        o.y = mv.y ? xv.y : xv.y * sc + bi;
        o.z = mv.z ? xv.z : xv.z * sc + bi;
        o.w = mv.w ? xv.w : xv.w * sc + bi;
        __builtin_nontemporal_store(o, &ov4[b * (DHW / 4) + xbase]);
    }
}

extern "C" void kernel_launch(void* const* d_in, const int* in_sizes, int n_in,
                              void* d_out, int out_size, void* d_ws, size_t ws_size,
                              hipStream_t stream) {
    const float* x     = (const float*)d_in[0];
    const int*   mask  = (const int*)d_in[1];
    const float* gamma = (const float*)d_in[2];
    const float* beta  = (const float*)d_in[3];
    float* out = (float*)d_out;

    channel_kernel<<<2 * DD, 1024, 0, stream>>>(x, mask, gamma, beta, out);
}

// Round 15
// 64.903 us; speedup vs baseline: 2.3373x; 1.3038x over previous
//
#include <hip/hip_runtime.h>

// Problem constants: b=32, d=256, h=32, w=128
#define BB 32
#define DD 256
#define HW 4096
#define DHW (DD * HW)        // 2^20
#define EPS 1e-5f

typedef float floatx4 __attribute__((ext_vector_type(4)));

// Best-known structure (R10, 64.9 us): one block per channel d, 1024 threads,
// single dispatch, no inter-block communication (each block's stats are
// block-local). Fabric traffic is optimal for exact computation:
//   134 MB phase-A HBM read + 134 MB phase-C L3-hit re-read + 131 MB write
//   ~= 399 MB at the measured ~6.15 TB/s mixed-stream fabric ceiling.
// (Measured floor arithmetic: exact stats require reading x twice; register/
// LDS residency cannot hold x (VGPR file ~= |x|); cross-block sync collapses
// streaming BW (R9/R13). Two-kernel variants pay the same 402 MB, all HBM,
// plus extra dispatch gaps.)
__global__ void __launch_bounds__(1024)
channel_kernel(const float* __restrict__ x, const int* __restrict__ mask,
               const float* __restrict__ gamma, const float* __restrict__ beta,
               float* __restrict__ out) {
    const int d = blockIdx.x;            // channel
    const int tid = threadIdx.x;         // 0..1023
    const int wave = tid >> 6, lane = tid & 63;

    const float4* __restrict__ xv4 = reinterpret_cast<const float4*>(x);
    const int4*   __restrict__ mv4 = reinterpret_cast<const int4*>(mask);
    const int xbase = d * 1024 + tid;    // float4 index of (b=0, d, 4*tid)

    // ---- Phase A: pure-streaming masked accumulation ----
    float sum = 0.f, sq = 0.f, cnt = 0.f;
#pragma unroll 8
    for (int b = 0; b < BB; ++b) {
        float4 xv = xv4[b * (DHW / 4) + xbase];
        int4  mv = mv4[b * 1024 + tid];
        if (!mv.x) { sum += xv.x; sq += xv.x * xv.x; cnt += 1.f; }
        if (!mv.y) { sum += xv.y; sq += xv.y * xv.y; cnt += 1.f; }
        if (!mv.z) { sum += xv.z; sq += xv.z * xv.z; cnt += 1.f; }
        if (!mv.w) { sum += xv.w; sq += xv.w * xv.w; cnt += 1.f; }
    }

    // ---- Phase B: block reduce (1024 -> 1), compute scale/bias ----
    __shared__ float rsum[16], rsq[16], rcnt[16];
    __shared__ float s_scale, s_bias;
#pragma unroll
    for (int off = 32; off > 0; off >>= 1) {
        sum += __shfl_down(sum, off);
        sq  += __shfl_down(sq, off);
        cnt += __shfl_down(cnt, off);
    }
    if (lane == 0) { rsum[wave] = sum; rsq[wave] = sq; rcnt[wave] = cnt; }
    __syncthreads();
    if (tid < 16) {
        float ts = rsum[tid], tq = rsq[tid], tc = rcnt[tid];
#pragma unroll
        for (int off = 8; off > 0; off >>= 1) {
            ts += __shfl_down(ts, off, 16);
            tq += __shfl_down(tq, off, 16);
            tc += __shfl_down(tc, off, 16);
        }
        if (tid == 0) {
            tc = fmaxf(tc, 1.0f);
            const float mean = ts / tc;
            const float var = fmaxf(tq / tc - mean * mean, 0.0f);
            const float sc = rsqrtf(var + EPS) * gamma[d];
            s_scale = sc;
            s_bias = beta[d] - mean * sc;
        }
    }
    __syncthreads();
    const float sc = s_scale, bi = s_bias;

    // ---- Phase C: re-read own 512 KB (in-kernel L3 hit) + nt-store out ----
    floatx4* __restrict__ ov4 = reinterpret_cast<floatx4*>(out);
#pragma unroll 8
    for (int b = 0; b < BB; ++b) {
        float4 xv = xv4[b * (DHW / 4) + xbase];
        int4  mv = mv4[b * 1024 + tid];
        floatx4 o;
        o.x = mv.x ? xv.x : xv.x * sc + bi;
        o.y = mv.y ? xv.y : xv.y * sc + bi;
        o.z = mv.z ? xv.z : xv.z * sc + bi;
        o.w = mv.w ? xv.w : xv.w * sc + bi;
        __builtin_nontemporal_store(o, &ov4[b * (DHW / 4) + xbase]);
    }
}

extern "C" void kernel_launch(void* const* d_in, const int* in_sizes, int n_in,
                              void* d_out, int out_size, void* d_ws, size_t ws_size,
                              hipStream_t stream) {
    const float* x     = (const float*)d_in[0];
    const int*   mask  = (const int*)d_in[1];
    const float* gamma = (const float*)d_in[2];
    const float* beta  = (const float*)d_in[3];
    float* out = (float*)d_out;

    channel_kernel<<<DD, 1024, 0, stream>>>(x, mask, gamma, beta, out);
}